// Round 7
// baseline (1009.046 us; speedup 1.0000x reference)
//
#include <hip/hip_runtime.h>
#include <hip/hip_bf16.h>

#define NB   16       // batches
#define NN   10000    // nodes per batch
#define NE   160000   // edges per batch
#define NODES (NB*NN) // 160000 total nodes
#define IN_F 19
#define HF   64
#define OUTF 32
#define LN_EPS 1e-5f
#define RANGE 625     // dst nodes per bucket (16 buckets/batch)
#define NCHUNK 32     // edge chunks per batch in bucket_kernel
#define CHSZ (NE/NCHUNK)   // 5000 edges per chunk
#define BCAP 16384    // bucket capacity (entries); mean 10000, sigma ~97

// R7 structure notes:
// * R6: conv was latency/TLP-bound (75us vs 17us FMA-issue floor; VALUBusy
//   27%, 625 blocks = 2.4/CU). Fix: 2 threads/node, output channels split by
//   WAVE (half = waveid&1) so weight rows stay wave-uniform (s_load path).
//   acc[32], grid 1250. LN does a cross-wave pair-reduce through 2KB LDS; the
//   same __syncthreads makes the in-place row update race-free (all reads of
//   a block's 128 rows precede the barrier, writes follow it).
// * agg: 2 edges/wave via 32-lane groups; lane loads a packed uint (2 bf16
//   channels); 8 edges in flight/iter; scalar index loads + cndmask select;
//   __shfl_xor(,32) cross-group reduce; 32-lane packed store.
// * CSR build: two-level binning (R6) -- line ownership without losing
//   parallelism. Kept unchanged.
// * bf16 for gathers/agg only; fp32 x for dense math + residual + LN.

__device__ inline unsigned pk_bf16(float a, float b) {
    __hip_bfloat162 h = __float22bfloat162_rn(float2{a, b});
    return *(unsigned*)&h;
}
__device__ inline float bflo(unsigned u) { return __uint_as_float(u << 16); }
__device__ inline float bfhi(unsigned u) { return __uint_as_float(u & 0xffff0000u); }

// ---------------- enc1: h = relu(nf@W1+b1), fully unrolled (k=19 const) ----------------
__global__ __launch_bounds__(256) void enc1_kernel(
    const float* __restrict__ nf,
    const float* __restrict__ w1, const float* __restrict__ b1,
    float* __restrict__ x)
{
    int node = blockIdx.x * 256 + threadIdx.x;   // 625*256 = 160000 exactly
    const float* p = nf + (size_t)node * IN_F;
    float a[IN_F];
#pragma unroll
    for (int k = 0; k < IN_F; ++k) a[k] = p[k];

    float h[HF];
#pragma unroll
    for (int j = 0; j < HF; ++j) h[j] = b1[j];
#pragma unroll
    for (int k = 0; k < IN_F; ++k) {
        float ak = a[k];
        const float* wr = w1 + k * HF;           // wave-uniform -> s_load
#pragma unroll
        for (int j = 0; j < HF; ++j) h[j] = fmaf(ak, wr[j], h[j]);
    }

    float4* dst = (float4*)(x + (size_t)node * HF);
#pragma unroll
    for (int q = 0; q < 16; ++q) {
        float4 v;
        v.x = fmaxf(h[4*q],   0.f); v.y = fmaxf(h[4*q+1], 0.f);
        v.z = fmaxf(h[4*q+2], 0.f); v.w = fmaxf(h[4*q+3], 0.f);
        dst[q] = v;
    }
}

// ---------------- gemm64: x = x@W + b in-place (2 threads/node); bf16 shadow xh ----------------
__global__ __launch_bounds__(256) void gemm64_kernel(
    float* __restrict__ x, const float* __restrict__ W, const float* __restrict__ bias,
    __hip_bfloat16* __restrict__ xh)
{
    int lane = threadIdx.x & 63;
    int waveid = threadIdx.x >> 6;               // 0..3
    int half = waveid & 1;                       // wave-uniform j-half
    int nib = (waveid >> 1) * 64 + lane;         // node-in-block 0..127
    int node = blockIdx.x * 128 + nib;
    const float* row = x + (size_t)node * HF;

    float acc[32];
    const float* b2 = bias + half * 32;
#pragma unroll
    for (int j = 0; j < 32; ++j) acc[j] = b2[j];

#pragma unroll 1
    for (int kc = 0; kc < HF; kc += 8) {
        float4 v0 = *(const float4*)(row + kc);
        float4 v1 = *(const float4*)(row + kc + 4);
        float av[8] = {v0.x, v0.y, v0.z, v0.w, v1.x, v1.y, v1.z, v1.w};
#pragma unroll
        for (int u = 0; u < 8; ++u) {
            const float* wr = W + (kc + u) * HF + half * 32;   // wave-uniform
#pragma unroll
            for (int j = 0; j < 32; ++j) acc[j] = fmaf(av[u], wr[j], acc[j]);
        }
    }

    __syncthreads();   // all reads of this block's 128 rows done -> in-place write safe

    float4* dst = (float4*)(x + (size_t)node * HF + half * 32);
#pragma unroll
    for (int q = 0; q < 8; ++q) {
        float4 v; v.x = acc[4*q]; v.y = acc[4*q+1]; v.z = acc[4*q+2]; v.w = acc[4*q+3];
        dst[q] = v;
    }
    uint4* hdst = (uint4*)(xh + (size_t)node * HF + half * 32);
#pragma unroll
    for (int q = 0; q < 4; ++q) {
        uint4 u;
        u.x = pk_bf16(acc[8*q+0], acc[8*q+1]);
        u.y = pk_bf16(acc[8*q+2], acc[8*q+3]);
        u.z = pk_bf16(acc[8*q+4], acc[8*q+5]);
        u.w = pk_bf16(acc[8*q+6], acc[8*q+7]);
        hdst[q] = u;
    }
}

// ---------------- bucket: bin edge chunks into per-(batch,range) buckets ----------------
__global__ __launch_bounds__(256) void bucket_kernel(const int* __restrict__ ei,
                                                     int* __restrict__ gcur,
                                                     unsigned* __restrict__ bkt)
{
    __shared__ int lcnt[16];
    __shared__ int lcur[16];
    __shared__ int gbase[16];
    int b = blockIdx.x >> 5;                     // NCHUNK=32 chunks per batch
    int chunk = blockIdx.x & 31;
    int t = threadIdx.x;
    if (t < 16) { lcnt[t] = 0; lcur[t] = 0; }
    __syncthreads();

    const int* srcp = ei + (size_t)b * 2 * NE + chunk * CHSZ;
    const int* dstp = srcp + NE;

    for (int e = t; e < CHSZ; e += 256)
        atomicAdd(&lcnt[(unsigned)dstp[e] / RANGE], 1);
    __syncthreads();
    if (t < 16) gbase[t] = atomicAdd(&gcur[b * 16 + t], lcnt[t]);
    __syncthreads();

    for (int e = t; e < CHSZ; e += 256) {
        int d = dstp[e];                          // L1-hot (2nd pass)
        int s = srcp[e];
        int j = (unsigned)d / RANGE;
        int ld = d - j * RANGE;
        int pos = gbase[j] + atomicAdd(&lcur[j], 1);
        if (pos < BCAP)
            bkt[(size_t)(b * 16 + j) * BCAP + pos] = (unsigned)s | ((unsigned)ld << 16);
    }
}

// ---------------- count2: per-bucket histogram -> cnt ----------------
__global__ __launch_bounds__(512) void count2_kernel(const unsigned* __restrict__ bkt,
                                                     const int* __restrict__ gcur,
                                                     int* __restrict__ cnt)
{
    __shared__ int lcnt[RANGE];
    int bid = blockIdx.x;                        // b*16 + j
    int b = bid >> 4, j = bid & 15;
    int t = threadIdx.x;
    for (int i = t; i < RANGE; i += 512) lcnt[i] = 0;
    __syncthreads();
    int n = min(gcur[bid], BCAP);
    const unsigned* bp = bkt + (size_t)bid * BCAP;
    for (int e = t; e < n; e += 512) atomicAdd(&lcnt[bp[e] >> 16], 1);
    __syncthreads();
    int base = b * NN + j * RANGE;
    for (int i = t; i < RANGE; i += 512) cnt[base + i] = lcnt[i];
}

// ---------------- scan: per-batch exclusive prefix over cnt ----------------
__global__ __launch_bounds__(256) void scan_kernel(const int* __restrict__ cnt, int* __restrict__ off)
{
    __shared__ int sdata[256];
    int b = blockIdx.x, t = threadIdx.x;
    const int CH = 40;                          // 256*40 = 10240 >= NN
    int lo = t * CH, hi = min(lo + CH, NN);
    int s = 0;
    for (int i = lo; i < hi; ++i) s += cnt[b * NN + i];
    sdata[t] = s;
    __syncthreads();
    for (int ofs = 1; ofs < 256; ofs <<= 1) {
        int v = (t >= ofs) ? sdata[t - ofs] : 0;
        __syncthreads();
        sdata[t] += v;
        __syncthreads();
    }
    int run = (t > 0) ? sdata[t - 1] : 0;       // exclusive prefix
    for (int i = lo; i < hi; ++i) { off[b * NN + i] = run; run += cnt[b * NN + i]; }
}

// ---------------- fill2: per-bucket fill of the block-owned CSR segment ----------------
__global__ __launch_bounds__(512) void fill2_kernel(const unsigned* __restrict__ bkt,
                                                    const int* __restrict__ gcur,
                                                    const int* __restrict__ off,
                                                    int* __restrict__ csr)
{
    __shared__ int lcur[RANGE];
    int bid = blockIdx.x;                        // b*16 + j
    int b = bid >> 4, j = bid & 15;
    int t = threadIdx.x;
    for (int i = t; i < RANGE; i += 512) lcur[i] = 0;
    __syncthreads();
    int n = min(gcur[bid], BCAP);
    const unsigned* bp = bkt + (size_t)bid * BCAP;
    const int* offb = off + b * NN + j * RANGE;
    int* csrb = csr + (size_t)b * NE;
    for (int e = t; e < n; e += 512) {
        unsigned u = bp[e];
        int ld = u >> 16;
        int pos = offb[ld] + atomicAdd(&lcur[ld], 1);
        csrb[pos] = (int)(u & 0xffffu);          // block-exclusive ~40KB segment
    }
}

// ---------------- mean aggregation: wave per node, 2 edges/iter-group, bf16 ----------------
__global__ __launch_bounds__(256) void agg_kernel(const __hip_bfloat16* __restrict__ xh,
                                                  const int* __restrict__ cnt,
                                                  const int* __restrict__ off,
                                                  const int* __restrict__ csr,
                                                  __hip_bfloat16* __restrict__ aggh)
{
    int b = blockIdx.x & 15;
    int chunk = blockIdx.x >> 4;                    // 0..2499
    int wid = threadIdx.x >> 6;                     // 4 waves = 4 nodes per block
    int n = chunk * 4 + wid;                        // 0..9999
    int w = b * NN + n;
    w = __builtin_amdgcn_readfirstlane(w);          // wave-uniform -> scalar loads
    int lane = threadIdx.x & 63;
    int g  = lane >> 5;                             // edge group 0/1
    int cl = lane & 31;                             // uint index = 2 channels
    int c = cnt[w];
    int o = off[w];
    const int* row = csr + (size_t)b * NE + o;      // uniform -> s_load
    const unsigned* xbu = (const unsigned*)(xh + (size_t)b * NN * HF);
    float a0 = 0.f, a1 = 0.f;
    int t = 0;
    for (; t + 8 <= c; t += 8) {                    // 8 edges/iter, 4 gathers in flight
        int i0 = row[t],   i1 = row[t+1], i2 = row[t+2], i3 = row[t+3];
        int i4 = row[t+4], i5 = row[t+5], i6 = row[t+6], i7 = row[t+7];
        int j0 = g ? i1 : i0;
        int j1 = g ? i3 : i2;
        int j2 = g ? i5 : i4;
        int j3 = g ? i7 : i6;
        unsigned u0 = xbu[(size_t)j0 * 32 + cl];
        unsigned u1 = xbu[(size_t)j1 * 32 + cl];
        unsigned u2 = xbu[(size_t)j2 * 32 + cl];
        unsigned u3 = xbu[(size_t)j3 * 32 + cl];
        a0 += bflo(u0); a1 += bfhi(u0);
        a0 += bflo(u1); a1 += bfhi(u1);
        a0 += bflo(u2); a1 += bfhi(u2);
        a0 += bflo(u3); a1 += bfhi(u3);
    }
    for (; t + 2 <= c; t += 2) {
        int i0 = row[t], i1 = row[t+1];
        int j = g ? i1 : i0;
        unsigned u = xbu[(size_t)j * 32 + cl];
        a0 += bflo(u); a1 += bfhi(u);
    }
    if (t < c && g == 0) {                          // odd leftover: group 0 only
        unsigned u = xbu[(size_t)row[t] * 32 + cl];
        a0 += bflo(u); a1 += bfhi(u);
    }
    a0 += __shfl_xor(a0, 32, 64);                   // cross-group reduce
    a1 += __shfl_xor(a1, 32, 64);
    float inv = (c > 0) ? 1.f / (float)c : 0.f;
    unsigned pk = pk_bf16(a0 * inv, a1 * inv);
    if (g == 0) ((unsigned*)aggh)[(size_t)w * 32 + cl] = pk;
}

// ---------------- conv: [x,agg]@W + b, +residual, LN, relu (2 threads/node) ----------------
__global__ __launch_bounds__(256) void conv_kernel(
    float* __restrict__ x, const __hip_bfloat16* __restrict__ aggh,
    const float* __restrict__ W, const float* __restrict__ bias,
    const float* __restrict__ g, const float* __restrict__ beta,
    __hip_bfloat16* __restrict__ xh)
{
    __shared__ float s1[2][128];
    __shared__ float s2[2][128];
    int lane = threadIdx.x & 63;
    int waveid = threadIdx.x >> 6;               // 0..3
    int half = waveid & 1;                       // wave-uniform j-half
    int nib = (waveid >> 1) * 64 + lane;         // node-in-block 0..127
    int node = blockIdx.x * 128 + nib;
    const float* xrow = x + (size_t)node * HF;
    const uint4* ap = (const uint4*)(aggh + (size_t)node * HF);   // 8 bf16/uint4

    float acc[32];
    const float* b2 = bias + half * 32;
#pragma unroll
    for (int j = 0; j < 32; ++j) acc[j] = b2[j];

    // agg half: W rows 64..127
#pragma unroll 1
    for (int kc = 0; kc < HF; kc += 8) {
        uint4 u = ap[kc >> 3];
        float av[8];
        av[0] = bflo(u.x); av[1] = bfhi(u.x);
        av[2] = bflo(u.y); av[3] = bfhi(u.y);
        av[4] = bflo(u.z); av[5] = bfhi(u.z);
        av[6] = bflo(u.w); av[7] = bfhi(u.w);
#pragma unroll
        for (int uu = 0; uu < 8; ++uu) {
            const float* wr = W + (HF + kc + uu) * HF + half * 32;  // wave-uniform
#pragma unroll
            for (int j = 0; j < 32; ++j) acc[j] = fmaf(av[uu], wr[j], acc[j]);
        }
    }

    // x half: W rows 0..63
#pragma unroll 1
    for (int kc = 0; kc < HF; kc += 8) {
        float4 v0 = *(const float4*)(xrow + kc);
        float4 v1 = *(const float4*)(xrow + kc + 4);
        float av[8] = {v0.x, v0.y, v0.z, v0.w, v1.x, v1.y, v1.z, v1.w};
#pragma unroll
        for (int uu = 0; uu < 8; ++uu) {
            const float* wr = W + (kc + uu) * HF + half * 32;
#pragma unroll
            for (int j = 0; j < 32; ++j) acc[j] = fmaf(av[uu], wr[j], acc[j]);
        }
    }

    // residual (own half, L1-hot) + partial sums for LN
    const float4* xr4 = (const float4*)(xrow + half * 32);
#pragma unroll
    for (int q = 0; q < 8; ++q) {
        float4 r = xr4[q];
        acc[4*q]   += r.x; acc[4*q+1] += r.y;
        acc[4*q+2] += r.z; acc[4*q+3] += r.w;
    }
    float ps = 0.f, pq = 0.f;
#pragma unroll
    for (int j = 0; j < 32; ++j) { ps += acc[j]; pq += acc[j] * acc[j]; }
    s1[half][nib] = ps;
    s2[half][nib] = pq;
    __syncthreads();   // also fences all reads of this block's rows before writes
    float sum = s1[0][nib] + s1[1][nib];
    float sq  = s2[0][nib] + s2[1][nib];
    float mu = sum * (1.f / HF);
    float var = sq * (1.f / HF) - mu * mu;
    float rs = rsqrtf(var + LN_EPS);

    const float* g2 = g + half * 32;
    const float* be2 = beta + half * 32;
#pragma unroll
    for (int j = 0; j < 32; ++j) {
        float y = (acc[j] - mu) * rs * g2[j] + be2[j];
        acc[j] = fmaxf(y, 0.f);
    }

    float4* dst = (float4*)(x + (size_t)node * HF + half * 32);
#pragma unroll
    for (int q = 0; q < 8; ++q) {
        float4 v; v.x = acc[4*q]; v.y = acc[4*q+1]; v.z = acc[4*q+2]; v.w = acc[4*q+3];
        dst[q] = v;
    }
    uint4* hdst = (uint4*)(xh + (size_t)node * HF + half * 32);
#pragma unroll
    for (int q = 0; q < 4; ++q) {
        uint4 u;
        u.x = pk_bf16(acc[8*q+0], acc[8*q+1]);
        u.y = pk_bf16(acc[8*q+2], acc[8*q+3]);
        u.z = pk_bf16(acc[8*q+4], acc[8*q+5]);
        u.w = pk_bf16(acc[8*q+6], acc[8*q+7]);
        hdst[q] = u;
    }
}

// ---------------- output head: out = x@out_w + out_b (2 threads/node) ----------------
__global__ __launch_bounds__(256) void out_kernel(const float* __restrict__ x,
                                                  const float* __restrict__ W,
                                                  const float* __restrict__ bias,
                                                  float* __restrict__ out)
{
    int lane = threadIdx.x & 63;
    int waveid = threadIdx.x >> 6;
    int half = waveid & 1;                       // wave-uniform j-half (16 outputs)
    int nib = (waveid >> 1) * 64 + lane;
    int node = blockIdx.x * 128 + nib;
    const float* row = x + (size_t)node * HF;

    float o[16];
    const float* b2 = bias + half * 16;
#pragma unroll
    for (int j = 0; j < 16; ++j) o[j] = b2[j];

#pragma unroll 1
    for (int kc = 0; kc < HF; kc += 8) {
        float4 v0 = *(const float4*)(row + kc);
        float4 v1 = *(const float4*)(row + kc + 4);
        float av[8] = {v0.x, v0.y, v0.z, v0.w, v1.x, v1.y, v1.z, v1.w};
#pragma unroll
        for (int u = 0; u < 8; ++u) {
            const float* wr = W + (kc + u) * OUTF + half * 16;   // wave-uniform
#pragma unroll
            for (int j = 0; j < 16; ++j) o[j] = fmaf(av[u], wr[j], o[j]);
        }
    }

    float4* dst = (float4*)(out + (size_t)node * OUTF + half * 16);
#pragma unroll
    for (int q = 0; q < 4; ++q) {
        float4 v; v.x = o[4*q]; v.y = o[4*q+1]; v.z = o[4*q+2]; v.w = o[4*q+3];
        dst[q] = v;
    }
}

extern "C" void kernel_launch(void* const* d_in, const int* in_sizes, int n_in,
                              void* d_out, int out_size, void* d_ws, size_t ws_size,
                              hipStream_t stream)
{
    const float* nf     = (const float*)d_in[0];
    const int*   ei     = (const int*)  d_in[1];   // edge_indices (B,2,E)
    const float* enc_w1 = (const float*)d_in[3];
    const float* enc_b1 = (const float*)d_in[4];
    const float* enc_w2 = (const float*)d_in[5];
    const float* enc_b2 = (const float*)d_in[6];
    const float* conv_w = (const float*)d_in[7];   // (3,128,64)
    const float* conv_b = (const float*)d_in[8];   // (3,64)
    const float* ln_g   = (const float*)d_in[9];
    const float* ln_b   = (const float*)d_in[10];
    const float* out_w  = (const float*)d_in[11];  // (64,32)
    const float* out_b  = (const float*)d_in[12];

    // workspace layout (~94 MB); bkt aliases agh (bucket data dead once fill2 runs)
    char* w = (char*)d_ws;
    float* x            = (float*)w;           w += (size_t)NODES * HF * sizeof(float);  // 41 MB
    __hip_bfloat16* xh  = (__hip_bfloat16*)w;  w += (size_t)NODES * HF * 2;              // 20.5 MB
    __hip_bfloat16* agh = (__hip_bfloat16*)w;  w += (size_t)NODES * HF * 2;              // 20.5 MB
    unsigned* bkt       = (unsigned*)agh;      // 256 buckets * 16384 * 4B = 16.8 MB
    int* cnt            = (int*)w;             w += (size_t)NODES * sizeof(int);
    int* off            = (int*)w;             w += (size_t)NODES * sizeof(int);
    int* csr            = (int*)w;             w += (size_t)NB * NE * sizeof(int);       // 10.24 MB
    int* gcur           = (int*)w;                                                       // 256 ints

    hipMemsetAsync(gcur, 0, 256 * sizeof(int), stream);

    enc1_kernel<<<NODES / 256, 256, 0, stream>>>(nf, enc_w1, enc_b1, x);
    gemm64_kernel<<<NODES / 128, 256, 0, stream>>>(x, enc_w2, enc_b2, xh);
    bucket_kernel<<<NB * NCHUNK, 256, 0, stream>>>(ei, gcur, bkt);
    count2_kernel<<<NB * 16, 512, 0, stream>>>(bkt, gcur, cnt);
    scan_kernel<<<NB, 256, 0, stream>>>(cnt, off);
    fill2_kernel<<<NB * 16, 512, 0, stream>>>(bkt, gcur, off, csr);

    for (int l = 0; l < 3; ++l) {
        agg_kernel<<<NODES / 4, 256, 0, stream>>>(xh, cnt, off, csr, agh);
        conv_kernel<<<NODES / 128, 256, 0, stream>>>(x, agh,
                                                     conv_w + (size_t)l * 2 * HF * HF,
                                                     conv_b + (size_t)l * HF,
                                                     ln_g + (size_t)l * HF,
                                                     ln_b + (size_t)l * HF,
                                                     xh);
    }
    out_kernel<<<NODES / 128, 256, 0, stream>>>(x, out_w, out_b, (float*)d_out);
}

// Round 8
// 554.694 us; speedup vs baseline: 1.8191x; 1.8191x over previous
//
#include <hip/hip_runtime.h>
#include <hip/hip_bf16.h>

#define NB   16       // batches
#define NN   10000    // nodes per batch
#define NE   160000   // edges per batch
#define NODES (NB*NN) // 160000 total nodes
#define IN_F 19
#define HF   64
#define OUTF 32
#define LN_EPS 1e-5f
#define RANGE 625     // dst nodes per bucket (16 buckets/batch)
#define NCHUNK 32     // edge chunks per batch in bucket_kernel
#define CHSZ (NE/NCHUNK)   // 5000 edges per chunk
#define BCAP 16384    // bucket capacity (entries); mean 10000, sigma ~97

// R8 structure notes:
// * R7 bug: half = waveid&1 is wave-uniform but LLVM divergence analysis
//   can't prove it (threadIdx-derived) -> weight loads fell off the s_load
//   path (SGPR 112->32, 2048 per-lane VMEM loads/thread, VALUBusy 10%).
//   Fix: __builtin_amdgcn_readfirstlane(half) pins uniformity -> weights
//   back to s_load + v_fmac(SGPR operand). Applied in gemm64/conv/out.
// * 2 threads/node output-split by wave (R7): doubles TLP vs R6's
//   latency-bound 2.4 blocks/CU; LN pair-reduce via 2KB LDS, the
//   __syncthreads also fences in-place row updates.
// * CSR build: two-level binning (R6) -- line ownership with parallelism.
// * bf16 for gathers/agg; fp32 x for dense math + residual + LN.

__device__ inline unsigned pk_bf16(float a, float b) {
    __hip_bfloat162 h = __float22bfloat162_rn(float2{a, b});
    return *(unsigned*)&h;
}
__device__ inline float bflo(unsigned u) { return __uint_as_float(u << 16); }
__device__ inline float bfhi(unsigned u) { return __uint_as_float(u & 0xffff0000u); }

// ---------------- enc1: h = relu(nf@W1+b1), fully unrolled (k=19 const) ----------------
__global__ __launch_bounds__(256) void enc1_kernel(
    const float* __restrict__ nf,
    const float* __restrict__ w1, const float* __restrict__ b1,
    float* __restrict__ x)
{
    int node = blockIdx.x * 256 + threadIdx.x;   // 625*256 = 160000 exactly
    const float* p = nf + (size_t)node * IN_F;
    float a[IN_F];
#pragma unroll
    for (int k = 0; k < IN_F; ++k) a[k] = p[k];

    float h[HF];
#pragma unroll
    for (int j = 0; j < HF; ++j) h[j] = b1[j];
#pragma unroll
    for (int k = 0; k < IN_F; ++k) {
        float ak = a[k];
        const float* wr = w1 + k * HF;           // wave-uniform -> s_load
#pragma unroll
        for (int j = 0; j < HF; ++j) h[j] = fmaf(ak, wr[j], h[j]);
    }

    float4* dst = (float4*)(x + (size_t)node * HF);
#pragma unroll
    for (int q = 0; q < 16; ++q) {
        float4 v;
        v.x = fmaxf(h[4*q],   0.f); v.y = fmaxf(h[4*q+1], 0.f);
        v.z = fmaxf(h[4*q+2], 0.f); v.w = fmaxf(h[4*q+3], 0.f);
        dst[q] = v;
    }
}

// ---------------- gemm64: x = x@W + b in-place (2 threads/node); bf16 shadow xh ----------------
__global__ __launch_bounds__(256) void gemm64_kernel(
    float* __restrict__ x, const float* __restrict__ W, const float* __restrict__ bias,
    __hip_bfloat16* __restrict__ xh)
{
    int lane = threadIdx.x & 63;
    int waveid = threadIdx.x >> 6;               // 0..3
    int half = __builtin_amdgcn_readfirstlane(waveid & 1);   // pin uniformity (R7 bug)
    int nib = (waveid >> 1) * 64 + lane;         // node-in-block 0..127
    int node = blockIdx.x * 128 + nib;
    const float* row = x + (size_t)node * HF;

    float acc[32];
    const float* b2 = bias + half * 32;
#pragma unroll
    for (int j = 0; j < 32; ++j) acc[j] = b2[j];

#pragma unroll 1
    for (int kc = 0; kc < HF; kc += 8) {
        float4 v0 = *(const float4*)(row + kc);
        float4 v1 = *(const float4*)(row + kc + 4);
        float av[8] = {v0.x, v0.y, v0.z, v0.w, v1.x, v1.y, v1.z, v1.w};
#pragma unroll
        for (int u = 0; u < 8; ++u) {
            const float* wr = W + (kc + u) * HF + half * 32;   // uniform -> s_load
#pragma unroll
            for (int j = 0; j < 32; ++j) acc[j] = fmaf(av[u], wr[j], acc[j]);
        }
    }

    __syncthreads();   // all reads of this block's 128 rows done -> in-place write safe

    float4* dst = (float4*)(x + (size_t)node * HF + half * 32);
#pragma unroll
    for (int q = 0; q < 8; ++q) {
        float4 v; v.x = acc[4*q]; v.y = acc[4*q+1]; v.z = acc[4*q+2]; v.w = acc[4*q+3];
        dst[q] = v;
    }
    uint4* hdst = (uint4*)(xh + (size_t)node * HF + half * 32);
#pragma unroll
    for (int q = 0; q < 4; ++q) {
        uint4 u;
        u.x = pk_bf16(acc[8*q+0], acc[8*q+1]);
        u.y = pk_bf16(acc[8*q+2], acc[8*q+3]);
        u.z = pk_bf16(acc[8*q+4], acc[8*q+5]);
        u.w = pk_bf16(acc[8*q+6], acc[8*q+7]);
        hdst[q] = u;
    }
}

// ---------------- bucket: bin edge chunks into per-(batch,range) buckets ----------------
__global__ __launch_bounds__(256) void bucket_kernel(const int* __restrict__ ei,
                                                     int* __restrict__ gcur,
                                                     unsigned* __restrict__ bkt)
{
    __shared__ int lcnt[16];
    __shared__ int lcur[16];
    __shared__ int gbase[16];
    int b = blockIdx.x >> 5;                     // NCHUNK=32 chunks per batch
    int chunk = blockIdx.x & 31;
    int t = threadIdx.x;
    if (t < 16) { lcnt[t] = 0; lcur[t] = 0; }
    __syncthreads();

    const int* srcp = ei + (size_t)b * 2 * NE + chunk * CHSZ;
    const int* dstp = srcp + NE;

    for (int e = t; e < CHSZ; e += 256)
        atomicAdd(&lcnt[(unsigned)dstp[e] / RANGE], 1);
    __syncthreads();
    if (t < 16) gbase[t] = atomicAdd(&gcur[b * 16 + t], lcnt[t]);
    __syncthreads();

    for (int e = t; e < CHSZ; e += 256) {
        int d = dstp[e];                          // L1-hot (2nd pass)
        int s = srcp[e];
        int j = (unsigned)d / RANGE;
        int ld = d - j * RANGE;
        int pos = gbase[j] + atomicAdd(&lcur[j], 1);
        if (pos < BCAP)
            bkt[(size_t)(b * 16 + j) * BCAP + pos] = (unsigned)s | ((unsigned)ld << 16);
    }
}

// ---------------- count2: per-bucket histogram -> cnt ----------------
__global__ __launch_bounds__(512) void count2_kernel(const unsigned* __restrict__ bkt,
                                                     const int* __restrict__ gcur,
                                                     int* __restrict__ cnt)
{
    __shared__ int lcnt[RANGE];
    int bid = blockIdx.x;                        // b*16 + j
    int b = bid >> 4, j = bid & 15;
    int t = threadIdx.x;
    for (int i = t; i < RANGE; i += 512) lcnt[i] = 0;
    __syncthreads();
    int n = min(gcur[bid], BCAP);
    const unsigned* bp = bkt + (size_t)bid * BCAP;
    for (int e = t; e < n; e += 512) atomicAdd(&lcnt[bp[e] >> 16], 1);
    __syncthreads();
    int base = b * NN + j * RANGE;
    for (int i = t; i < RANGE; i += 512) cnt[base + i] = lcnt[i];
}

// ---------------- scan: per-batch exclusive prefix over cnt ----------------
__global__ __launch_bounds__(256) void scan_kernel(const int* __restrict__ cnt, int* __restrict__ off)
{
    __shared__ int sdata[256];
    int b = blockIdx.x, t = threadIdx.x;
    const int CH = 40;                          // 256*40 = 10240 >= NN
    int lo = t * CH, hi = min(lo + CH, NN);
    int s = 0;
    for (int i = lo; i < hi; ++i) s += cnt[b * NN + i];
    sdata[t] = s;
    __syncthreads();
    for (int ofs = 1; ofs < 256; ofs <<= 1) {
        int v = (t >= ofs) ? sdata[t - ofs] : 0;
        __syncthreads();
        sdata[t] += v;
        __syncthreads();
    }
    int run = (t > 0) ? sdata[t - 1] : 0;       // exclusive prefix
    for (int i = lo; i < hi; ++i) { off[b * NN + i] = run; run += cnt[b * NN + i]; }
}

// ---------------- fill2: per-bucket fill of the block-owned CSR segment ----------------
__global__ __launch_bounds__(512) void fill2_kernel(const unsigned* __restrict__ bkt,
                                                    const int* __restrict__ gcur,
                                                    const int* __restrict__ off,
                                                    int* __restrict__ csr)
{
    __shared__ int lcur[RANGE];
    int bid = blockIdx.x;                        // b*16 + j
    int b = bid >> 4, j = bid & 15;
    int t = threadIdx.x;
    for (int i = t; i < RANGE; i += 512) lcur[i] = 0;
    __syncthreads();
    int n = min(gcur[bid], BCAP);
    const unsigned* bp = bkt + (size_t)bid * BCAP;
    const int* offb = off + b * NN + j * RANGE;
    int* csrb = csr + (size_t)b * NE;
    for (int e = t; e < n; e += 512) {
        unsigned u = bp[e];
        int ld = u >> 16;
        int pos = offb[ld] + atomicAdd(&lcur[ld], 1);
        csrb[pos] = (int)(u & 0xffffu);          // block-exclusive ~40KB segment
    }
}

// ---------------- mean aggregation: wave per node, 2 edges/iter-group, bf16 ----------------
__global__ __launch_bounds__(256) void agg_kernel(const __hip_bfloat16* __restrict__ xh,
                                                  const int* __restrict__ cnt,
                                                  const int* __restrict__ off,
                                                  const int* __restrict__ csr,
                                                  __hip_bfloat16* __restrict__ aggh)
{
    int b = blockIdx.x & 15;
    int chunk = blockIdx.x >> 4;                    // 0..2499
    int wid = threadIdx.x >> 6;                     // 4 waves = 4 nodes per block
    int n = chunk * 4 + wid;                        // 0..9999
    int w = b * NN + n;
    w = __builtin_amdgcn_readfirstlane(w);          // wave-uniform -> scalar loads
    int lane = threadIdx.x & 63;
    int g  = lane >> 5;                             // edge group 0/1
    int cl = lane & 31;                             // uint index = 2 channels
    int c = cnt[w];
    int o = off[w];
    const int* row = csr + (size_t)b * NE + o;      // uniform -> s_load
    const unsigned* xbu = (const unsigned*)(xh + (size_t)b * NN * HF);
    float a0 = 0.f, a1 = 0.f;
    int t = 0;
    for (; t + 8 <= c; t += 8) {                    // 8 edges/iter, 4 gathers in flight
        int i0 = row[t],   i1 = row[t+1], i2 = row[t+2], i3 = row[t+3];
        int i4 = row[t+4], i5 = row[t+5], i6 = row[t+6], i7 = row[t+7];
        int j0 = g ? i1 : i0;
        int j1 = g ? i3 : i2;
        int j2 = g ? i5 : i4;
        int j3 = g ? i7 : i6;
        unsigned u0 = xbu[(size_t)j0 * 32 + cl];
        unsigned u1 = xbu[(size_t)j1 * 32 + cl];
        unsigned u2 = xbu[(size_t)j2 * 32 + cl];
        unsigned u3 = xbu[(size_t)j3 * 32 + cl];
        a0 += bflo(u0); a1 += bfhi(u0);
        a0 += bflo(u1); a1 += bfhi(u1);
        a0 += bflo(u2); a1 += bfhi(u2);
        a0 += bflo(u3); a1 += bfhi(u3);
    }
    for (; t + 2 <= c; t += 2) {
        int i0 = row[t], i1 = row[t+1];
        int j = g ? i1 : i0;
        unsigned u = xbu[(size_t)j * 32 + cl];
        a0 += bflo(u); a1 += bfhi(u);
    }
    if (t < c && g == 0) {                          // odd leftover: group 0 only
        unsigned u = xbu[(size_t)row[t] * 32 + cl];
        a0 += bflo(u); a1 += bfhi(u);
    }
    a0 += __shfl_xor(a0, 32, 64);                   // cross-group reduce
    a1 += __shfl_xor(a1, 32, 64);
    float inv = (c > 0) ? 1.f / (float)c : 0.f;
    unsigned pk = pk_bf16(a0 * inv, a1 * inv);
    if (g == 0) ((unsigned*)aggh)[(size_t)w * 32 + cl] = pk;
}

// ---------------- conv: [x,agg]@W + b, +residual, LN, relu (2 threads/node) ----------------
__global__ __launch_bounds__(256) void conv_kernel(
    float* __restrict__ x, const __hip_bfloat16* __restrict__ aggh,
    const float* __restrict__ W, const float* __restrict__ bias,
    const float* __restrict__ g, const float* __restrict__ beta,
    __hip_bfloat16* __restrict__ xh)
{
    __shared__ float s1[2][128];
    __shared__ float s2[2][128];
    int lane = threadIdx.x & 63;
    int waveid = threadIdx.x >> 6;               // 0..3
    int half = __builtin_amdgcn_readfirstlane(waveid & 1);   // pin uniformity (R7 bug)
    int nib = (waveid >> 1) * 64 + lane;         // node-in-block 0..127
    int node = blockIdx.x * 128 + nib;
    const float* xrow = x + (size_t)node * HF;
    const uint4* ap = (const uint4*)(aggh + (size_t)node * HF);   // 8 bf16/uint4

    float acc[32];
    const float* b2 = bias + half * 32;
#pragma unroll
    for (int j = 0; j < 32; ++j) acc[j] = b2[j];

    // agg half: W rows 64..127
#pragma unroll 1
    for (int kc = 0; kc < HF; kc += 8) {
        uint4 u = ap[kc >> 3];
        float av[8];
        av[0] = bflo(u.x); av[1] = bfhi(u.x);
        av[2] = bflo(u.y); av[3] = bfhi(u.y);
        av[4] = bflo(u.z); av[5] = bfhi(u.z);
        av[6] = bflo(u.w); av[7] = bfhi(u.w);
#pragma unroll
        for (int uu = 0; uu < 8; ++uu) {
            const float* wr = W + (HF + kc + uu) * HF + half * 32;  // uniform -> s_load
#pragma unroll
            for (int j = 0; j < 32; ++j) acc[j] = fmaf(av[uu], wr[j], acc[j]);
        }
    }

    // x half: W rows 0..63
#pragma unroll 1
    for (int kc = 0; kc < HF; kc += 8) {
        float4 v0 = *(const float4*)(xrow + kc);
        float4 v1 = *(const float4*)(xrow + kc + 4);
        float av[8] = {v0.x, v0.y, v0.z, v0.w, v1.x, v1.y, v1.z, v1.w};
#pragma unroll
        for (int uu = 0; uu < 8; ++uu) {
            const float* wr = W + (kc + uu) * HF + half * 32;
#pragma unroll
            for (int j = 0; j < 32; ++j) acc[j] = fmaf(av[uu], wr[j], acc[j]);
        }
    }

    // residual (own half, L1-hot) + partial sums for LN
    const float4* xr4 = (const float4*)(xrow + half * 32);
#pragma unroll
    for (int q = 0; q < 8; ++q) {
        float4 r = xr4[q];
        acc[4*q]   += r.x; acc[4*q+1] += r.y;
        acc[4*q+2] += r.z; acc[4*q+3] += r.w;
    }
    float ps = 0.f, pq = 0.f;
#pragma unroll
    for (int j = 0; j < 32; ++j) { ps += acc[j]; pq += acc[j] * acc[j]; }
    s1[half][nib] = ps;
    s2[half][nib] = pq;
    __syncthreads();   // also fences all reads of this block's rows before writes
    float sum = s1[0][nib] + s1[1][nib];
    float sq  = s2[0][nib] + s2[1][nib];
    float mu = sum * (1.f / HF);
    float var = sq * (1.f / HF) - mu * mu;
    float rs = rsqrtf(var + LN_EPS);

    const float* g2 = g + half * 32;
    const float* be2 = beta + half * 32;
#pragma unroll
    for (int j = 0; j < 32; ++j) {
        float y = (acc[j] - mu) * rs * g2[j] + be2[j];
        acc[j] = fmaxf(y, 0.f);
    }

    float4* dst = (float4*)(x + (size_t)node * HF + half * 32);
#pragma unroll
    for (int q = 0; q < 8; ++q) {
        float4 v; v.x = acc[4*q]; v.y = acc[4*q+1]; v.z = acc[4*q+2]; v.w = acc[4*q+3];
        dst[q] = v;
    }
    uint4* hdst = (uint4*)(xh + (size_t)node * HF + half * 32);
#pragma unroll
    for (int q = 0; q < 4; ++q) {
        uint4 u;
        u.x = pk_bf16(acc[8*q+0], acc[8*q+1]);
        u.y = pk_bf16(acc[8*q+2], acc[8*q+3]);
        u.z = pk_bf16(acc[8*q+4], acc[8*q+5]);
        u.w = pk_bf16(acc[8*q+6], acc[8*q+7]);
        hdst[q] = u;
    }
}

// ---------------- output head: out = x@out_w + out_b (2 threads/node) ----------------
__global__ __launch_bounds__(256) void out_kernel(const float* __restrict__ x,
                                                  const float* __restrict__ W,
                                                  const float* __restrict__ bias,
                                                  float* __restrict__ out)
{
    int lane = threadIdx.x & 63;
    int waveid = threadIdx.x >> 6;
    int half = __builtin_amdgcn_readfirstlane(waveid & 1);   // pin uniformity (R7 bug)
    int nib = (waveid >> 1) * 64 + lane;
    int node = blockIdx.x * 128 + nib;
    const float* row = x + (size_t)node * HF;

    float o[16];
    const float* b2 = bias + half * 16;
#pragma unroll
    for (int j = 0; j < 16; ++j) o[j] = b2[j];

#pragma unroll 1
    for (int kc = 0; kc < HF; kc += 8) {
        float4 v0 = *(const float4*)(row + kc);
        float4 v1 = *(const float4*)(row + kc + 4);
        float av[8] = {v0.x, v0.y, v0.z, v0.w, v1.x, v1.y, v1.z, v1.w};
#pragma unroll
        for (int u = 0; u < 8; ++u) {
            const float* wr = W + (kc + u) * OUTF + half * 16;   // uniform -> s_load
#pragma unroll
            for (int j = 0; j < 16; ++j) o[j] = fmaf(av[u], wr[j], o[j]);
        }
    }

    float4* dst = (float4*)(out + (size_t)node * OUTF + half * 16);
#pragma unroll
    for (int q = 0; q < 4; ++q) {
        float4 v; v.x = o[4*q]; v.y = o[4*q+1]; v.z = o[4*q+2]; v.w = o[4*q+3];
        dst[q] = v;
    }
}

extern "C" void kernel_launch(void* const* d_in, const int* in_sizes, int n_in,
                              void* d_out, int out_size, void* d_ws, size_t ws_size,
                              hipStream_t stream)
{
    const float* nf     = (const float*)d_in[0];
    const int*   ei     = (const int*)  d_in[1];   // edge_indices (B,2,E)
    const float* enc_w1 = (const float*)d_in[3];
    const float* enc_b1 = (const float*)d_in[4];
    const float* enc_w2 = (const float*)d_in[5];
    const float* enc_b2 = (const float*)d_in[6];
    const float* conv_w = (const float*)d_in[7];   // (3,128,64)
    const float* conv_b = (const float*)d_in[8];   // (3,64)
    const float* ln_g   = (const float*)d_in[9];
    const float* ln_b   = (const float*)d_in[10];
    const float* out_w  = (const float*)d_in[11];  // (64,32)
    const float* out_b  = (const float*)d_in[12];

    // workspace layout (~94 MB); bkt aliases agh (bucket data dead once fill2 runs)
    char* w = (char*)d_ws;
    float* x            = (float*)w;           w += (size_t)NODES * HF * sizeof(float);  // 41 MB
    __hip_bfloat16* xh  = (__hip_bfloat16*)w;  w += (size_t)NODES * HF * 2;              // 20.5 MB
    __hip_bfloat16* agh = (__hip_bfloat16*)w;  w += (size_t)NODES * HF * 2;              // 20.5 MB
    unsigned* bkt       = (unsigned*)agh;      // 256 buckets * 16384 * 4B = 16.8 MB
    int* cnt            = (int*)w;             w += (size_t)NODES * sizeof(int);
    int* off            = (int*)w;             w += (size_t)NODES * sizeof(int);
    int* csr            = (int*)w;             w += (size_t)NB * NE * sizeof(int);       // 10.24 MB
    int* gcur           = (int*)w;                                                       // 256 ints

    hipMemsetAsync(gcur, 0, 256 * sizeof(int), stream);

    enc1_kernel<<<NODES / 256, 256, 0, stream>>>(nf, enc_w1, enc_b1, x);
    gemm64_kernel<<<NODES / 128, 256, 0, stream>>>(x, enc_w2, enc_b2, xh);
    bucket_kernel<<<NB * NCHUNK, 256, 0, stream>>>(ei, gcur, bkt);
    count2_kernel<<<NB * 16, 512, 0, stream>>>(bkt, gcur, cnt);
    scan_kernel<<<NB, 256, 0, stream>>>(cnt, off);
    fill2_kernel<<<NB * 16, 512, 0, stream>>>(bkt, gcur, off, csr);

    for (int l = 0; l < 3; ++l) {
        agg_kernel<<<NODES / 4, 256, 0, stream>>>(xh, cnt, off, csr, agh);
        conv_kernel<<<NODES / 128, 256, 0, stream>>>(x, agh,
                                                     conv_w + (size_t)l * 2 * HF * HF,
                                                     conv_b + (size_t)l * HF,
                                                     ln_g + (size_t)l * HF,
                                                     ln_b + (size_t)l * HF,
                                                     xh);
    }
    out_kernel<<<NODES / 128, 256, 0, stream>>>(x, out_w, out_b, (float*)d_out);
}

// Round 9
// 460.171 us; speedup vs baseline: 2.1928x; 1.2054x over previous
//
#include <hip/hip_runtime.h>
#include <hip/hip_bf16.h>

#define NB   16       // batches
#define NN   10000    // nodes per batch
#define NE   160000   // edges per batch
#define NODES (NB*NN) // 160000 total nodes
#define IN_F 19
#define HF   64
#define OUTF 32
#define LN_EPS 1e-5f
#define RANGE 625     // dst nodes per bucket (16 buckets/batch)
#define NCHUNK 32     // edge chunks per batch in bucket_kernel
#define CHSZ (NE/NCHUNK)   // 5000 edges per chunk
#define BCAP 16384    // bucket capacity (entries); mean 10000, sigma ~97

// R9 structure notes:
// * State is bf16-only (xh); fp32 x dropped. All accumulation / residual /
//   LN in fp32 registers; only row storage is rounded. Cuts conv traffic
//   123->61.5 MB, gemm64 102->41, enc1/out -20 MB each. Error budget:
//   ~0.002 abs per rounding on O(1) LN outputs -> absmax ~0.02-0.03 vs
//   threshold 0.065.
// * 2 threads/node, output half split by wave; half pinned wave-uniform via
//   __builtin_amdgcn_readfirstlane (R7: divergence analysis can't prove
//   waveid&1 uniform -> weight loads fell off the s_load path, 3x slower).
// * LN: cross-wave pair reduce via 2KB LDS; the __syncthreads also fences
//   the in-place row writes (all row reads precede it).
// * CSR build: two-level binning (R6) -- line ownership with parallelism
//   (R4 edge-scatter: 117MB writes; R5 monolithic owners: no parallelism).
// * Weight rows stay fp32, wave-uniform -> s_load + v_fmac(SGPR operand).

__device__ inline unsigned pk_bf16(float a, float b) {
    __hip_bfloat162 h = __float22bfloat162_rn(float2{a, b});
    return *(unsigned*)&h;
}
__device__ inline float bflo(unsigned u) { return __uint_as_float(u << 16); }
__device__ inline float bfhi(unsigned u) { return __uint_as_float(u & 0xffff0000u); }

// ---------------- enc1: xh = relu(nf@W1+b1) in bf16 ----------------
__global__ __launch_bounds__(256) void enc1_kernel(
    const float* __restrict__ nf,
    const float* __restrict__ w1, const float* __restrict__ b1,
    __hip_bfloat16* __restrict__ xh)
{
    int node = blockIdx.x * 256 + threadIdx.x;   // 625*256 = 160000 exactly
    const float* p = nf + (size_t)node * IN_F;
    float a[IN_F];
#pragma unroll
    for (int k = 0; k < IN_F; ++k) a[k] = p[k];

    float h[HF];
#pragma unroll
    for (int j = 0; j < HF; ++j) h[j] = b1[j];
#pragma unroll
    for (int k = 0; k < IN_F; ++k) {
        float ak = a[k];
        const float* wr = w1 + k * HF;           // wave-uniform -> s_load
#pragma unroll
        for (int j = 0; j < HF; ++j) h[j] = fmaf(ak, wr[j], h[j]);
    }

    uint4* dst = (uint4*)(xh + (size_t)node * HF);
#pragma unroll
    for (int q = 0; q < 8; ++q) {
        uint4 u;
        u.x = pk_bf16(fmaxf(h[8*q+0],0.f), fmaxf(h[8*q+1],0.f));
        u.y = pk_bf16(fmaxf(h[8*q+2],0.f), fmaxf(h[8*q+3],0.f));
        u.z = pk_bf16(fmaxf(h[8*q+4],0.f), fmaxf(h[8*q+5],0.f));
        u.w = pk_bf16(fmaxf(h[8*q+6],0.f), fmaxf(h[8*q+7],0.f));
        dst[q] = u;
    }
}

// ---------------- gemm64: xh = xh@W + b in-place (2 threads/node) ----------------
__global__ __launch_bounds__(256) void gemm64_kernel(
    __hip_bfloat16* __restrict__ xh, const float* __restrict__ W, const float* __restrict__ bias)
{
    int lane = threadIdx.x & 63;
    int waveid = threadIdx.x >> 6;               // 0..3
    int half = __builtin_amdgcn_readfirstlane(waveid & 1);   // pin uniformity
    int nib = (waveid >> 1) * 64 + lane;         // node-in-block 0..127
    int node = blockIdx.x * 128 + nib;
    const uint4* rp = (const uint4*)(xh + (size_t)node * HF);   // 8 ch per uint4

    float acc[32];
    const float* b2 = bias + half * 32;
#pragma unroll
    for (int j = 0; j < 32; ++j) acc[j] = b2[j];

#pragma unroll 1
    for (int kc = 0; kc < HF; kc += 16) {
        uint4 u0 = rp[kc >> 3];
        uint4 u1 = rp[(kc >> 3) + 1];
        float av[16];
        av[0]=bflo(u0.x); av[1]=bfhi(u0.x); av[2]=bflo(u0.y); av[3]=bfhi(u0.y);
        av[4]=bflo(u0.z); av[5]=bfhi(u0.z); av[6]=bflo(u0.w); av[7]=bfhi(u0.w);
        av[8]=bflo(u1.x); av[9]=bfhi(u1.x); av[10]=bflo(u1.y); av[11]=bfhi(u1.y);
        av[12]=bflo(u1.z); av[13]=bfhi(u1.z); av[14]=bflo(u1.w); av[15]=bfhi(u1.w);
#pragma unroll
        for (int u = 0; u < 16; ++u) {
            const float* wr = W + (kc + u) * HF + half * 32;   // uniform -> s_load
#pragma unroll
            for (int j = 0; j < 32; ++j) acc[j] = fmaf(av[u], wr[j], acc[j]);
        }
    }

    __syncthreads();   // all reads of this block's 128 rows done -> in-place write safe

    uint4* hdst = (uint4*)(xh + (size_t)node * HF + half * 32);
#pragma unroll
    for (int q = 0; q < 4; ++q) {
        uint4 u;
        u.x = pk_bf16(acc[8*q+0], acc[8*q+1]);
        u.y = pk_bf16(acc[8*q+2], acc[8*q+3]);
        u.z = pk_bf16(acc[8*q+4], acc[8*q+5]);
        u.w = pk_bf16(acc[8*q+6], acc[8*q+7]);
        hdst[q] = u;
    }
}

// ---------------- bucket: bin edge chunks into per-(batch,range) buckets ----------------
__global__ __launch_bounds__(256) void bucket_kernel(const int* __restrict__ ei,
                                                     int* __restrict__ gcur,
                                                     unsigned* __restrict__ bkt)
{
    __shared__ int lcnt[16];
    __shared__ int lcur[16];
    __shared__ int gbase[16];
    int b = blockIdx.x >> 5;                     // NCHUNK=32 chunks per batch
    int chunk = blockIdx.x & 31;
    int t = threadIdx.x;
    if (t < 16) { lcnt[t] = 0; lcur[t] = 0; }
    __syncthreads();

    const int* srcp = ei + (size_t)b * 2 * NE + chunk * CHSZ;
    const int* dstp = srcp + NE;

    for (int e = t; e < CHSZ; e += 256)
        atomicAdd(&lcnt[(unsigned)dstp[e] / RANGE], 1);
    __syncthreads();
    if (t < 16) gbase[t] = atomicAdd(&gcur[b * 16 + t], lcnt[t]);
    __syncthreads();

    for (int e = t; e < CHSZ; e += 256) {
        int d = dstp[e];                          // L1-hot (2nd pass)
        int s = srcp[e];
        int j = (unsigned)d / RANGE;
        int ld = d - j * RANGE;
        int pos = gbase[j] + atomicAdd(&lcur[j], 1);
        if (pos < BCAP)
            bkt[(size_t)(b * 16 + j) * BCAP + pos] = (unsigned)s | ((unsigned)ld << 16);
    }
}

// ---------------- count2: per-bucket histogram -> cnt ----------------
__global__ __launch_bounds__(512) void count2_kernel(const unsigned* __restrict__ bkt,
                                                     const int* __restrict__ gcur,
                                                     int* __restrict__ cnt)
{
    __shared__ int lcnt[RANGE];
    int bid = blockIdx.x;                        // b*16 + j
    int b = bid >> 4, j = bid & 15;
    int t = threadIdx.x;
    for (int i = t; i < RANGE; i += 512) lcnt[i] = 0;
    __syncthreads();
    int n = min(gcur[bid], BCAP);
    const unsigned* bp = bkt + (size_t)bid * BCAP;
    for (int e = t; e < n; e += 512) atomicAdd(&lcnt[bp[e] >> 16], 1);
    __syncthreads();
    int base = b * NN + j * RANGE;
    for (int i = t; i < RANGE; i += 512) cnt[base + i] = lcnt[i];
}

// ---------------- scan: per-batch exclusive prefix over cnt ----------------
__global__ __launch_bounds__(256) void scan_kernel(const int* __restrict__ cnt, int* __restrict__ off)
{
    __shared__ int sdata[256];
    int b = blockIdx.x, t = threadIdx.x;
    const int CH = 40;                          // 256*40 = 10240 >= NN
    int lo = t * CH, hi = min(lo + CH, NN);
    int s = 0;
    for (int i = lo; i < hi; ++i) s += cnt[b * NN + i];
    sdata[t] = s;
    __syncthreads();
    for (int ofs = 1; ofs < 256; ofs <<= 1) {
        int v = (t >= ofs) ? sdata[t - ofs] : 0;
        __syncthreads();
        sdata[t] += v;
        __syncthreads();
    }
    int run = (t > 0) ? sdata[t - 1] : 0;       // exclusive prefix
    for (int i = lo; i < hi; ++i) { off[b * NN + i] = run; run += cnt[b * NN + i]; }
}

// ---------------- fill2: per-bucket fill of the block-owned CSR segment ----------------
__global__ __launch_bounds__(512) void fill2_kernel(const unsigned* __restrict__ bkt,
                                                    const int* __restrict__ gcur,
                                                    const int* __restrict__ off,
                                                    int* __restrict__ csr)
{
    __shared__ int lcur[RANGE];
    int bid = blockIdx.x;                        // b*16 + j
    int b = bid >> 4, j = bid & 15;
    int t = threadIdx.x;
    for (int i = t; i < RANGE; i += 512) lcur[i] = 0;
    __syncthreads();
    int n = min(gcur[bid], BCAP);
    const unsigned* bp = bkt + (size_t)bid * BCAP;
    const int* offb = off + b * NN + j * RANGE;
    int* csrb = csr + (size_t)b * NE;
    for (int e = t; e < n; e += 512) {
        unsigned u = bp[e];
        int ld = u >> 16;
        int pos = offb[ld] + atomicAdd(&lcur[ld], 1);
        csrb[pos] = (int)(u & 0xffffu);          // block-exclusive ~40KB segment
    }
}

// ---------------- mean aggregation: wave per node, 2 edges/iter-group, bf16 ----------------
__global__ __launch_bounds__(256) void agg_kernel(const __hip_bfloat16* __restrict__ xh,
                                                  const int* __restrict__ cnt,
                                                  const int* __restrict__ off,
                                                  const int* __restrict__ csr,
                                                  __hip_bfloat16* __restrict__ aggh)
{
    int b = blockIdx.x & 15;
    int chunk = blockIdx.x >> 4;                    // 0..2499
    int wid = threadIdx.x >> 6;                     // 4 waves = 4 nodes per block
    int n = chunk * 4 + wid;                        // 0..9999
    int w = b * NN + n;
    w = __builtin_amdgcn_readfirstlane(w);          // wave-uniform -> scalar loads
    int lane = threadIdx.x & 63;
    int g  = lane >> 5;                             // edge group 0/1
    int cl = lane & 31;                             // uint index = 2 channels
    int c = cnt[w];
    int o = off[w];
    const int* row = csr + (size_t)b * NE + o;      // uniform -> s_load
    const unsigned* xbu = (const unsigned*)(xh + (size_t)b * NN * HF);
    float a0 = 0.f, a1 = 0.f;
    int t = 0;
    for (; t + 8 <= c; t += 8) {                    // 8 edges/iter, 4 gathers in flight
        int i0 = row[t],   i1 = row[t+1], i2 = row[t+2], i3 = row[t+3];
        int i4 = row[t+4], i5 = row[t+5], i6 = row[t+6], i7 = row[t+7];
        int j0 = g ? i1 : i0;
        int j1 = g ? i3 : i2;
        int j2 = g ? i5 : i4;
        int j3 = g ? i7 : i6;
        unsigned u0 = xbu[(size_t)j0 * 32 + cl];
        unsigned u1 = xbu[(size_t)j1 * 32 + cl];
        unsigned u2 = xbu[(size_t)j2 * 32 + cl];
        unsigned u3 = xbu[(size_t)j3 * 32 + cl];
        a0 += bflo(u0); a1 += bfhi(u0);
        a0 += bflo(u1); a1 += bfhi(u1);
        a0 += bflo(u2); a1 += bfhi(u2);
        a0 += bflo(u3); a1 += bfhi(u3);
    }
    for (; t + 2 <= c; t += 2) {
        int i0 = row[t], i1 = row[t+1];
        int j = g ? i1 : i0;
        unsigned u = xbu[(size_t)j * 32 + cl];
        a0 += bflo(u); a1 += bfhi(u);
    }
    if (t < c && g == 0) {                          // odd leftover: group 0 only
        unsigned u = xbu[(size_t)row[t] * 32 + cl];
        a0 += bflo(u); a1 += bfhi(u);
    }
    a0 += __shfl_xor(a0, 32, 64);                   // cross-group reduce
    a1 += __shfl_xor(a1, 32, 64);
    float inv = (c > 0) ? 1.f / (float)c : 0.f;
    unsigned pk = pk_bf16(a0 * inv, a1 * inv);
    if (g == 0) ((unsigned*)aggh)[(size_t)w * 32 + cl] = pk;
}

// ---------------- conv: xh = relu(LN([xh,agg]@W + b + xh)) (2 threads/node) ----------------
__global__ __launch_bounds__(256) void conv_kernel(
    __hip_bfloat16* __restrict__ xh, const __hip_bfloat16* __restrict__ aggh,
    const float* __restrict__ W, const float* __restrict__ bias,
    const float* __restrict__ g, const float* __restrict__ beta)
{
    __shared__ float s1[2][128];
    __shared__ float s2[2][128];
    int lane = threadIdx.x & 63;
    int waveid = threadIdx.x >> 6;               // 0..3
    int half = __builtin_amdgcn_readfirstlane(waveid & 1);   // pin uniformity
    int nib = (waveid >> 1) * 64 + lane;         // node-in-block 0..127
    int node = blockIdx.x * 128 + nib;
    const uint4* xp = (const uint4*)(xh   + (size_t)node * HF);
    const uint4* ap = (const uint4*)(aggh + (size_t)node * HF);

    float acc[32];
    const float* b2 = bias + half * 32;
#pragma unroll
    for (int j = 0; j < 32; ++j) acc[j] = b2[j];

    // agg half: W rows 64..127
#pragma unroll 1
    for (int kc = 0; kc < HF; kc += 16) {
        uint4 u0 = ap[kc >> 3];
        uint4 u1 = ap[(kc >> 3) + 1];
        float av[16];
        av[0]=bflo(u0.x); av[1]=bfhi(u0.x); av[2]=bflo(u0.y); av[3]=bfhi(u0.y);
        av[4]=bflo(u0.z); av[5]=bfhi(u0.z); av[6]=bflo(u0.w); av[7]=bfhi(u0.w);
        av[8]=bflo(u1.x); av[9]=bfhi(u1.x); av[10]=bflo(u1.y); av[11]=bfhi(u1.y);
        av[12]=bflo(u1.z); av[13]=bfhi(u1.z); av[14]=bflo(u1.w); av[15]=bfhi(u1.w);
#pragma unroll
        for (int uu = 0; uu < 16; ++uu) {
            const float* wr = W + (HF + kc + uu) * HF + half * 32;  // uniform -> s_load
#pragma unroll
            for (int j = 0; j < 32; ++j) acc[j] = fmaf(av[uu], wr[j], acc[j]);
        }
    }

    // x half: W rows 0..63
#pragma unroll 1
    for (int kc = 0; kc < HF; kc += 16) {
        uint4 u0 = xp[kc >> 3];
        uint4 u1 = xp[(kc >> 3) + 1];
        float av[16];
        av[0]=bflo(u0.x); av[1]=bfhi(u0.x); av[2]=bflo(u0.y); av[3]=bfhi(u0.y);
        av[4]=bflo(u0.z); av[5]=bfhi(u0.z); av[6]=bflo(u0.w); av[7]=bfhi(u0.w);
        av[8]=bflo(u1.x); av[9]=bfhi(u1.x); av[10]=bflo(u1.y); av[11]=bfhi(u1.y);
        av[12]=bflo(u1.z); av[13]=bfhi(u1.z); av[14]=bflo(u1.w); av[15]=bfhi(u1.w);
#pragma unroll
        for (int uu = 0; uu < 16; ++uu) {
            const float* wr = W + (kc + uu) * HF + half * 32;
#pragma unroll
            for (int j = 0; j < 32; ++j) acc[j] = fmaf(av[uu], wr[j], acc[j]);
        }
    }

    // residual: reload own half (L1-hot) + partial sums for LN
    const uint4* xr = (const uint4*)(xh + (size_t)node * HF + half * 32);
#pragma unroll
    for (int q = 0; q < 4; ++q) {
        uint4 u = xr[q];
        acc[8*q+0] += bflo(u.x); acc[8*q+1] += bfhi(u.x);
        acc[8*q+2] += bflo(u.y); acc[8*q+3] += bfhi(u.y);
        acc[8*q+4] += bflo(u.z); acc[8*q+5] += bfhi(u.z);
        acc[8*q+6] += bflo(u.w); acc[8*q+7] += bfhi(u.w);
    }
    float ps = 0.f, pq = 0.f;
#pragma unroll
    for (int j = 0; j < 32; ++j) { ps += acc[j]; pq += acc[j] * acc[j]; }
    s1[half][nib] = ps;
    s2[half][nib] = pq;
    __syncthreads();   // also fences all row reads before in-place writes
    float sum = s1[0][nib] + s1[1][nib];
    float sq  = s2[0][nib] + s2[1][nib];
    float mu = sum * (1.f / HF);
    float var = sq * (1.f / HF) - mu * mu;
    float rs = rsqrtf(var + LN_EPS);

    const float* g2 = g + half * 32;
    const float* be2 = beta + half * 32;
#pragma unroll
    for (int j = 0; j < 32; ++j) {
        float y = (acc[j] - mu) * rs * g2[j] + be2[j];
        acc[j] = fmaxf(y, 0.f);
    }

    uint4* hdst = (uint4*)(xh + (size_t)node * HF + half * 32);
#pragma unroll
    for (int q = 0; q < 4; ++q) {
        uint4 u;
        u.x = pk_bf16(acc[8*q+0], acc[8*q+1]);
        u.y = pk_bf16(acc[8*q+2], acc[8*q+3]);
        u.z = pk_bf16(acc[8*q+4], acc[8*q+5]);
        u.w = pk_bf16(acc[8*q+6], acc[8*q+7]);
        hdst[q] = u;
    }
}

// ---------------- output head: out = xh@out_w + out_b (2 threads/node, fp32 out) ----------------
__global__ __launch_bounds__(256) void out_kernel(const __hip_bfloat16* __restrict__ xh,
                                                  const float* __restrict__ W,
                                                  const float* __restrict__ bias,
                                                  float* __restrict__ out)
{
    int lane = threadIdx.x & 63;
    int waveid = threadIdx.x >> 6;
    int half = __builtin_amdgcn_readfirstlane(waveid & 1);   // pin uniformity
    int nib = (waveid >> 1) * 64 + lane;
    int node = blockIdx.x * 128 + nib;
    const uint4* rp = (const uint4*)(xh + (size_t)node * HF);

    float o[16];
    const float* b2 = bias + half * 16;
#pragma unroll
    for (int j = 0; j < 16; ++j) o[j] = b2[j];

#pragma unroll 1
    for (int kc = 0; kc < HF; kc += 16) {
        uint4 u0 = rp[kc >> 3];
        uint4 u1 = rp[(kc >> 3) + 1];
        float av[16];
        av[0]=bflo(u0.x); av[1]=bfhi(u0.x); av[2]=bflo(u0.y); av[3]=bfhi(u0.y);
        av[4]=bflo(u0.z); av[5]=bfhi(u0.z); av[6]=bflo(u0.w); av[7]=bfhi(u0.w);
        av[8]=bflo(u1.x); av[9]=bfhi(u1.x); av[10]=bflo(u1.y); av[11]=bfhi(u1.y);
        av[12]=bflo(u1.z); av[13]=bfhi(u1.z); av[14]=bflo(u1.w); av[15]=bfhi(u1.w);
#pragma unroll
        for (int u = 0; u < 16; ++u) {
            const float* wr = W + (kc + u) * OUTF + half * 16;   // uniform -> s_load
#pragma unroll
            for (int j = 0; j < 16; ++j) o[j] = fmaf(av[u], wr[j], o[j]);
        }
    }

    float4* dst = (float4*)(out + (size_t)node * OUTF + half * 16);
#pragma unroll
    for (int q = 0; q < 4; ++q) {
        float4 v; v.x = o[4*q]; v.y = o[4*q+1]; v.z = o[4*q+2]; v.w = o[4*q+3];
        dst[q] = v;
    }
}

extern "C" void kernel_launch(void* const* d_in, const int* in_sizes, int n_in,
                              void* d_out, int out_size, void* d_ws, size_t ws_size,
                              hipStream_t stream)
{
    const float* nf     = (const float*)d_in[0];
    const int*   ei     = (const int*)  d_in[1];   // edge_indices (B,2,E)
    const float* enc_w1 = (const float*)d_in[3];
    const float* enc_b1 = (const float*)d_in[4];
    const float* enc_w2 = (const float*)d_in[5];
    const float* enc_b2 = (const float*)d_in[6];
    const float* conv_w = (const float*)d_in[7];   // (3,128,64)
    const float* conv_b = (const float*)d_in[8];   // (3,64)
    const float* ln_g   = (const float*)d_in[9];
    const float* ln_b   = (const float*)d_in[10];
    const float* out_w  = (const float*)d_in[11];  // (64,32)
    const float* out_b  = (const float*)d_in[12];

    // workspace (~53 MB); bkt aliases agh (bucket data dead once fill2 runs)
    char* w = (char*)d_ws;
    __hip_bfloat16* xh  = (__hip_bfloat16*)w;  w += (size_t)NODES * HF * 2;              // 20.5 MB
    __hip_bfloat16* agh = (__hip_bfloat16*)w;  w += (size_t)NODES * HF * 2;              // 20.5 MB
    unsigned* bkt       = (unsigned*)agh;      // 256 buckets * 16384 * 4B = 16.8 MB
    int* cnt            = (int*)w;             w += (size_t)NODES * sizeof(int);
    int* off            = (int*)w;             w += (size_t)NODES * sizeof(int);
    int* csr            = (int*)w;             w += (size_t)NB * NE * sizeof(int);       // 10.24 MB
    int* gcur           = (int*)w;                                                       // 256 ints

    hipMemsetAsync(gcur, 0, 256 * sizeof(int), stream);

    enc1_kernel<<<NODES / 256, 256, 0, stream>>>(nf, enc_w1, enc_b1, xh);
    gemm64_kernel<<<NODES / 128, 256, 0, stream>>>(xh, enc_w2, enc_b2);
    bucket_kernel<<<NB * NCHUNK, 256, 0, stream>>>(ei, gcur, bkt);
    count2_kernel<<<NB * 16, 512, 0, stream>>>(bkt, gcur, cnt);
    scan_kernel<<<NB, 256, 0, stream>>>(cnt, off);
    fill2_kernel<<<NB * 16, 512, 0, stream>>>(bkt, gcur, off, csr);

    for (int l = 0; l < 3; ++l) {
        agg_kernel<<<NODES / 4, 256, 0, stream>>>(xh, cnt, off, csr, agh);
        conv_kernel<<<NODES / 128, 256, 0, stream>>>(xh, agh,
                                                     conv_w + (size_t)l * 2 * HF * HF,
                                                     conv_b + (size_t)l * HF,
                                                     ln_g + (size_t)l * HF,
                                                     ln_b + (size_t)l * HF);
    }
    out_kernel<<<NODES / 128, 256, 0, stream>>>(xh, out_w, out_b, (float*)d_out);
}

// Round 13
// 454.977 us; speedup vs baseline: 2.2178x; 1.0114x over previous
//
#include <hip/hip_runtime.h>
#include <hip/hip_fp16.h>

#define NB   16       // batches
#define NN   10000    // nodes per batch
#define NE   160000   // edges per batch
#define NODES (NB*NN) // 160000 total nodes
#define IN_F 19
#define HF   64
#define OUTF 32
#define LN_EPS 1e-5f
#define RANGE 625     // dst nodes per bucket (16 buckets/batch)
#define NCHUNK 32     // edge chunks per batch in bucket_kernel
#define CHSZ (NE/NCHUNK)   // 5000 edges per chunk
#define BCAP 16384    // bucket capacity (entries); mean 10000, sigma ~97

// R13 structure notes (BISECTION ROUND):
// * R10(bf16 MFMA conv) and R12(fp16 MFMA conv) failed at the BIT-IDENTICAL
//   absmax 0.078125 -- dtype-independent => deterministic defect in the
//   shared MFMA conv path (wprep+conv), not rounding. Three inspection
//   passes found nothing; so bisect: conv reverted to the R8/R9-proven VALU
//   structure (2 thr/node, fp32 weights via s_load), everything else stays
//   fp16. Outcome disambiguates: absmax ~0.01 => storage-rounding model
//   right + MFMA path convicted; ~0.03+ => error source is elsewhere.
// * State fp16 (11-bit mantissa, range-safe: post-LN O(1-5), weights ~0.35).
// * VALU dense kernels: readfirstlane-pinned wave-uniform weight rows ->
//   s_load + v_fmac(SGPR) (R7 lesson).
// * CSR build: two-level binning (R6) -- line ownership with parallelism.

__device__ inline unsigned pk_f16(float a, float b) {
    __half2 h = __float22half2_rn(float2{a, b});
    return *(unsigned*)&h;
}
__device__ inline float2 upk_f16(unsigned u) {
    __half2 h = *(__half2*)&u;
    return __half22float2(h);
}

// ---------------- enc1: xh = relu(nf@W1+b1) in fp16 ----------------
__global__ __launch_bounds__(256) void enc1_kernel(
    const float* __restrict__ nf,
    const float* __restrict__ w1, const float* __restrict__ b1,
    __half* __restrict__ xh)
{
    int node = blockIdx.x * 256 + threadIdx.x;   // 625*256 = 160000 exactly
    const float* p = nf + (size_t)node * IN_F;
    float a[IN_F];
#pragma unroll
    for (int k = 0; k < IN_F; ++k) a[k] = p[k];

    float h[HF];
#pragma unroll
    for (int j = 0; j < HF; ++j) h[j] = b1[j];
#pragma unroll
    for (int k = 0; k < IN_F; ++k) {
        float ak = a[k];
        const float* wr = w1 + k * HF;           // wave-uniform -> s_load
#pragma unroll
        for (int j = 0; j < HF; ++j) h[j] = fmaf(ak, wr[j], h[j]);
    }

    uint4* dst = (uint4*)(xh + (size_t)node * HF);
#pragma unroll
    for (int q = 0; q < 8; ++q) {
        uint4 u;
        u.x = pk_f16(fmaxf(h[8*q+0],0.f), fmaxf(h[8*q+1],0.f));
        u.y = pk_f16(fmaxf(h[8*q+2],0.f), fmaxf(h[8*q+3],0.f));
        u.z = pk_f16(fmaxf(h[8*q+4],0.f), fmaxf(h[8*q+5],0.f));
        u.w = pk_f16(fmaxf(h[8*q+6],0.f), fmaxf(h[8*q+7],0.f));
        dst[q] = u;
    }
}

// ---------------- gemm64: xh = xh@W + b in-place (2 threads/node) ----------------
__global__ __launch_bounds__(256) void gemm64_kernel(
    __half* __restrict__ xh, const float* __restrict__ W, const float* __restrict__ bias)
{
    int lane = threadIdx.x & 63;
    int waveid = threadIdx.x >> 6;               // 0..3
    int half = __builtin_amdgcn_readfirstlane(waveid & 1);   // pin uniformity
    int nib = (waveid >> 1) * 64 + lane;         // node-in-block 0..127
    int node = blockIdx.x * 128 + nib;
    const uint4* rp = (const uint4*)(xh + (size_t)node * HF);   // 8 ch per uint4

    float acc[32];
    const float* b2 = bias + half * 32;
#pragma unroll
    for (int j = 0; j < 32; ++j) acc[j] = b2[j];

#pragma unroll 1
    for (int kc = 0; kc < HF; kc += 16) {
        uint4 u0 = rp[kc >> 3];
        uint4 u1 = rp[(kc >> 3) + 1];
        float av[16];
        float2 f;
        f = upk_f16(u0.x); av[0]=f.x;  av[1]=f.y;
        f = upk_f16(u0.y); av[2]=f.x;  av[3]=f.y;
        f = upk_f16(u0.z); av[4]=f.x;  av[5]=f.y;
        f = upk_f16(u0.w); av[6]=f.x;  av[7]=f.y;
        f = upk_f16(u1.x); av[8]=f.x;  av[9]=f.y;
        f = upk_f16(u1.y); av[10]=f.x; av[11]=f.y;
        f = upk_f16(u1.z); av[12]=f.x; av[13]=f.y;
        f = upk_f16(u1.w); av[14]=f.x; av[15]=f.y;
#pragma unroll
        for (int u = 0; u < 16; ++u) {
            const float* wr = W + (kc + u) * HF + half * 32;   // uniform -> s_load
#pragma unroll
            for (int j = 0; j < 32; ++j) acc[j] = fmaf(av[u], wr[j], acc[j]);
        }
    }

    __syncthreads();   // all reads of this block's 128 rows done -> in-place write safe

    uint4* hdst = (uint4*)(xh + (size_t)node * HF + half * 32);
#pragma unroll
    for (int q = 0; q < 4; ++q) {
        uint4 u;
        u.x = pk_f16(acc[8*q+0], acc[8*q+1]);
        u.y = pk_f16(acc[8*q+2], acc[8*q+3]);
        u.z = pk_f16(acc[8*q+4], acc[8*q+5]);
        u.w = pk_f16(acc[8*q+6], acc[8*q+7]);
        hdst[q] = u;
    }
}

// ---------------- bucket: bin edge chunks into per-(batch,range) buckets ----------------
__global__ __launch_bounds__(256) void bucket_kernel(const int* __restrict__ ei,
                                                     int* __restrict__ gcur,
                                                     unsigned* __restrict__ bkt)
{
    __shared__ int lcnt[16];
    __shared__ int lcur[16];
    __shared__ int gbase[16];
    int b = blockIdx.x >> 5;                     // NCHUNK=32 chunks per batch
    int chunk = blockIdx.x & 31;
    int t = threadIdx.x;
    if (t < 16) { lcnt[t] = 0; lcur[t] = 0; }
    __syncthreads();

    const int* srcp = ei + (size_t)b * 2 * NE + chunk * CHSZ;
    const int* dstp = srcp + NE;

    for (int e = t; e < CHSZ; e += 256)
        atomicAdd(&lcnt[(unsigned)dstp[e] / RANGE], 1);
    __syncthreads();
    if (t < 16) gbase[t] = atomicAdd(&gcur[b * 16 + t], lcnt[t]);
    __syncthreads();

    for (int e = t; e < CHSZ; e += 256) {
        int d = dstp[e];                          // L1-hot (2nd pass)
        int s = srcp[e];
        int j = (unsigned)d / RANGE;
        int ld = d - j * RANGE;
        int pos = gbase[j] + atomicAdd(&lcur[j], 1);
        if (pos < BCAP)
            bkt[(size_t)(b * 16 + j) * BCAP + pos] = (unsigned)s | ((unsigned)ld << 16);
    }
}

// ---------------- count2: per-bucket histogram -> cnt ----------------
__global__ __launch_bounds__(512) void count2_kernel(const unsigned* __restrict__ bkt,
                                                     const int* __restrict__ gcur,
                                                     int* __restrict__ cnt)
{
    __shared__ int lcnt[RANGE];
    int bid = blockIdx.x;                        // b*16 + j
    int b = bid >> 4, j = bid & 15;
    int t = threadIdx.x;
    for (int i = t; i < RANGE; i += 512) lcnt[i] = 0;
    __syncthreads();
    int n = min(gcur[bid], BCAP);
    const unsigned* bp = bkt + (size_t)bid * BCAP;
    for (int e = t; e < n; e += 512) atomicAdd(&lcnt[bp[e] >> 16], 1);
    __syncthreads();
    int base = b * NN + j * RANGE;
    for (int i = t; i < RANGE; i += 512) cnt[base + i] = lcnt[i];
}

// ---------------- scan: per-batch exclusive prefix over cnt ----------------
__global__ __launch_bounds__(256) void scan_kernel(const int* __restrict__ cnt, int* __restrict__ off)
{
    __shared__ int sdata[256];
    int b = blockIdx.x, t = threadIdx.x;
    const int CH = 40;                          // 256*40 = 10240 >= NN
    int lo = t * CH, hi = min(lo + CH, NN);
    int s = 0;
    for (int i = lo; i < hi; ++i) s += cnt[b * NN + i];
    sdata[t] = s;
    __syncthreads();
    for (int ofs = 1; ofs < 256; ofs <<= 1) {
        int v = (t >= ofs) ? sdata[t - ofs] : 0;
        __syncthreads();
        sdata[t] += v;
        __syncthreads();
    }
    int run = (t > 0) ? sdata[t - 1] : 0;       // exclusive prefix
    for (int i = lo; i < hi; ++i) { off[b * NN + i] = run; run += cnt[b * NN + i]; }
}

// ---------------- fill2: per-bucket fill of the block-owned CSR segment ----------------
__global__ __launch_bounds__(512) void fill2_kernel(const unsigned* __restrict__ bkt,
                                                    const int* __restrict__ gcur,
                                                    const int* __restrict__ off,
                                                    int* __restrict__ csr)
{
    __shared__ int lcur[RANGE];
    int bid = blockIdx.x;                        // b*16 + j
    int b = bid >> 4, j = bid & 15;
    int t = threadIdx.x;
    for (int i = t; i < RANGE; i += 512) lcur[i] = 0;
    __syncthreads();
    int n = min(gcur[bid], BCAP);
    const unsigned* bp = bkt + (size_t)bid * BCAP;
    const int* offb = off + b * NN + j * RANGE;
    int* csrb = csr + (size_t)b * NE;
    for (int e = t; e < n; e += 512) {
        unsigned u = bp[e];
        int ld = u >> 16;
        int pos = offb[ld] + atomicAdd(&lcur[ld], 1);
        csrb[pos] = (int)(u & 0xffffu);          // block-exclusive ~40KB segment
    }
}

// ---------------- mean aggregation: wave per node, 2 edges/iter-group, fp16 ----------------
__global__ __launch_bounds__(256) void agg_kernel(const __half* __restrict__ xh,
                                                  const int* __restrict__ cnt,
                                                  const int* __restrict__ off,
                                                  const int* __restrict__ csr,
                                                  __half* __restrict__ aggh)
{
    int b = blockIdx.x & 15;
    int chunk = blockIdx.x >> 4;                    // 0..2499
    int wid = threadIdx.x >> 6;                     // 4 waves = 4 nodes per block
    int n = chunk * 4 + wid;                        // 0..9999
    int w = b * NN + n;
    w = __builtin_amdgcn_readfirstlane(w);          // wave-uniform -> scalar loads
    int lane = threadIdx.x & 63;
    int g  = lane >> 5;                             // edge group 0/1
    int cl = lane & 31;                             // uint index = 2 channels
    int c = cnt[w];
    int o = off[w];
    const int* row = csr + (size_t)b * NE + o;      // uniform -> s_load
    const unsigned* xbu = (const unsigned*)(xh + (size_t)b * NN * HF);
    float a0 = 0.f, a1 = 0.f;
    int t = 0;
    for (; t + 8 <= c; t += 8) {                    // 8 edges/iter, 4 gathers in flight
        int i0 = row[t],   i1 = row[t+1], i2 = row[t+2], i3 = row[t+3];
        int i4 = row[t+4], i5 = row[t+5], i6 = row[t+6], i7 = row[t+7];
        int j0 = g ? i1 : i0;
        int j1 = g ? i3 : i2;
        int j2 = g ? i5 : i4;
        int j3 = g ? i7 : i6;
        unsigned u0 = xbu[(size_t)j0 * 32 + cl];
        unsigned u1 = xbu[(size_t)j1 * 32 + cl];
        unsigned u2 = xbu[(size_t)j2 * 32 + cl];
        unsigned u3 = xbu[(size_t)j3 * 32 + cl];
        float2 f0 = upk_f16(u0), f1 = upk_f16(u1), f2 = upk_f16(u2), f3 = upk_f16(u3);
        a0 += f0.x; a1 += f0.y;
        a0 += f1.x; a1 += f1.y;
        a0 += f2.x; a1 += f2.y;
        a0 += f3.x; a1 += f3.y;
    }
    for (; t + 2 <= c; t += 2) {
        int i0 = row[t], i1 = row[t+1];
        int j = g ? i1 : i0;
        float2 f = upk_f16(xbu[(size_t)j * 32 + cl]);
        a0 += f.x; a1 += f.y;
    }
    if (t < c && g == 0) {                          // odd leftover: group 0 only
        float2 f = upk_f16(xbu[(size_t)row[t] * 32 + cl]);
        a0 += f.x; a1 += f.y;
    }
    a0 += __shfl_xor(a0, 32, 64);                   // cross-group reduce
    a1 += __shfl_xor(a1, 32, 64);
    float inv = (c > 0) ? 1.f / (float)c : 0.f;
    unsigned pk = pk_f16(a0 * inv, a1 * inv);
    if (g == 0) ((unsigned*)aggh)[(size_t)w * 32 + cl] = pk;
}

// ---------------- conv (VALU, R8/R9-proven): xh = relu(LN([xh,agg]@W + b + xh)) ----------------
__global__ __launch_bounds__(256) void conv_kernel(
    __half* __restrict__ xh, const __half* __restrict__ aggh,
    const float* __restrict__ W, const float* __restrict__ bias,
    const float* __restrict__ g, const float* __restrict__ beta)
{
    __shared__ float s1[2][128];
    __shared__ float s2[2][128];
    int lane = threadIdx.x & 63;
    int waveid = threadIdx.x >> 6;               // 0..3
    int half = __builtin_amdgcn_readfirstlane(waveid & 1);   // pin uniformity
    int nib = (waveid >> 1) * 64 + lane;         // node-in-block 0..127
    int node = blockIdx.x * 128 + nib;
    const uint4* xp = (const uint4*)(xh   + (size_t)node * HF);
    const uint4* ap = (const uint4*)(aggh + (size_t)node * HF);

    float acc[32];
    const float* b2 = bias + half * 32;
#pragma unroll
    for (int j = 0; j < 32; ++j) acc[j] = b2[j];

    // agg half: W rows 64..127
#pragma unroll 1
    for (int kc = 0; kc < HF; kc += 16) {
        uint4 u0 = ap[kc >> 3];
        uint4 u1 = ap[(kc >> 3) + 1];
        float av[16];
        float2 f;
        f = upk_f16(u0.x); av[0]=f.x;  av[1]=f.y;
        f = upk_f16(u0.y); av[2]=f.x;  av[3]=f.y;
        f = upk_f16(u0.z); av[4]=f.x;  av[5]=f.y;
        f = upk_f16(u0.w); av[6]=f.x;  av[7]=f.y;
        f = upk_f16(u1.x); av[8]=f.x;  av[9]=f.y;
        f = upk_f16(u1.y); av[10]=f.x; av[11]=f.y;
        f = upk_f16(u1.z); av[12]=f.x; av[13]=f.y;
        f = upk_f16(u1.w); av[14]=f.x; av[15]=f.y;
#pragma unroll
        for (int uu = 0; uu < 16; ++uu) {
            const float* wr = W + (HF + kc + uu) * HF + half * 32;  // uniform -> s_load
#pragma unroll
            for (int j = 0; j < 32; ++j) acc[j] = fmaf(av[uu], wr[j], acc[j]);
        }
    }

    // x half: W rows 0..63
#pragma unroll 1
    for (int kc = 0; kc < HF; kc += 16) {
        uint4 u0 = xp[kc >> 3];
        uint4 u1 = xp[(kc >> 3) + 1];
        float av[16];
        float2 f;
        f = upk_f16(u0.x); av[0]=f.x;  av[1]=f.y;
        f = upk_f16(u0.y); av[2]=f.x;  av[3]=f.y;
        f = upk_f16(u0.z); av[4]=f.x;  av[5]=f.y;
        f = upk_f16(u0.w); av[6]=f.x;  av[7]=f.y;
        f = upk_f16(u1.x); av[8]=f.x;  av[9]=f.y;
        f = upk_f16(u1.y); av[10]=f.x; av[11]=f.y;
        f = upk_f16(u1.z); av[12]=f.x; av[13]=f.y;
        f = upk_f16(u1.w); av[14]=f.x; av[15]=f.y;
#pragma unroll
        for (int uu = 0; uu < 16; ++uu) {
            const float* wr = W + (kc + uu) * HF + half * 32;
#pragma unroll
            for (int j = 0; j < 32; ++j) acc[j] = fmaf(av[uu], wr[j], acc[j]);
        }
    }

    // residual: reload own half (L1-hot) + partial sums for LN
    const uint4* xr = (const uint4*)(xh + (size_t)node * HF + half * 32);
#pragma unroll
    for (int q = 0; q < 4; ++q) {
        uint4 u = xr[q];
        float2 f;
        f = upk_f16(u.x); acc[8*q+0] += f.x; acc[8*q+1] += f.y;
        f = upk_f16(u.y); acc[8*q+2] += f.x; acc[8*q+3] += f.y;
        f = upk_f16(u.z); acc[8*q+4] += f.x; acc[8*q+5] += f.y;
        f = upk_f16(u.w); acc[8*q+6] += f.x; acc[8*q+7] += f.y;
    }
    float ps = 0.f, pq = 0.f;
#pragma unroll
    for (int j = 0; j < 32; ++j) { ps += acc[j]; pq += acc[j] * acc[j]; }
    s1[half][nib] = ps;
    s2[half][nib] = pq;
    __syncthreads();   // also fences all row reads before in-place writes
    float sum = s1[0][nib] + s1[1][nib];
    float sq  = s2[0][nib] + s2[1][nib];
    float mu = sum * (1.f / HF);
    float var = sq * (1.f / HF) - mu * mu;
    float rs = rsqrtf(var + LN_EPS);

    const float* g2 = g + half * 32;
    const float* be2 = beta + half * 32;
#pragma unroll
    for (int j = 0; j < 32; ++j) {
        float y = (acc[j] - mu) * rs * g2[j] + be2[j];
        acc[j] = fmaxf(y, 0.f);
    }

    uint4* hdst = (uint4*)(xh + (size_t)node * HF + half * 32);
#pragma unroll
    for (int q = 0; q < 4; ++q) {
        uint4 u;
        u.x = pk_f16(acc[8*q+0], acc[8*q+1]);
        u.y = pk_f16(acc[8*q+2], acc[8*q+3]);
        u.z = pk_f16(acc[8*q+4], acc[8*q+5]);
        u.w = pk_f16(acc[8*q+6], acc[8*q+7]);
        hdst[q] = u;
    }
}

// ---------------- output head: out = xh@out_w + out_b (2 threads/node, fp32 out) ----------------
__global__ __launch_bounds__(256) void out_kernel(const __half* __restrict__ xh,
                                                  const float* __restrict__ W,
                                                  const float* __restrict__ bias,
                                                  float* __restrict__ out)
{
    int lane = threadIdx.x & 63;
    int waveid = threadIdx.x >> 6;
    int half = __builtin_amdgcn_readfirstlane(waveid & 1);   // pin uniformity
    int nib = (waveid >> 1) * 64 + lane;
    int node = blockIdx.x * 128 + nib;
    const uint4* rp = (const uint4*)(xh + (size_t)node * HF);

    float o[16];
    const float* b2 = bias + half * 16;
#pragma unroll
    for (int j = 0; j < 16; ++j) o[j] = b2[j];

#pragma unroll 1
    for (int kc = 0; kc < HF; kc += 16) {
        uint4 u0 = rp[kc >> 3];
        uint4 u1 = rp[(kc >> 3) + 1];
        float av[16];
        float2 f;
        f = upk_f16(u0.x); av[0]=f.x;  av[1]=f.y;
        f = upk_f16(u0.y); av[2]=f.x;  av[3]=f.y;
        f = upk_f16(u0.z); av[4]=f.x;  av[5]=f.y;
        f = upk_f16(u0.w); av[6]=f.x;  av[7]=f.y;
        f = upk_f16(u1.x); av[8]=f.x;  av[9]=f.y;
        f = upk_f16(u1.y); av[10]=f.x; av[11]=f.y;
        f = upk_f16(u1.z); av[12]=f.x; av[13]=f.y;
        f = upk_f16(u1.w); av[14]=f.x; av[15]=f.y;
#pragma unroll
        for (int u = 0; u < 16; ++u) {
            const float* wr = W + (kc + u) * OUTF + half * 16;   // uniform -> s_load
#pragma unroll
            for (int j = 0; j < 16; ++j) o[j] = fmaf(av[u], wr[j], o[j]);
        }
    }

    float4* dst = (float4*)(out + (size_t)node * OUTF + half * 16);
#pragma unroll
    for (int q = 0; q < 4; ++q) {
        float4 v; v.x = o[4*q]; v.y = o[4*q+1]; v.z = o[4*q+2]; v.w = o[4*q+3];
        dst[q] = v;
    }
}

extern "C" void kernel_launch(void* const* d_in, const int* in_sizes, int n_in,
                              void* d_out, int out_size, void* d_ws, size_t ws_size,
                              hipStream_t stream)
{
    const float* nf     = (const float*)d_in[0];
    const int*   ei     = (const int*)  d_in[1];   // edge_indices (B,2,E)
    const float* enc_w1 = (const float*)d_in[3];
    const float* enc_b1 = (const float*)d_in[4];
    const float* enc_w2 = (const float*)d_in[5];
    const float* enc_b2 = (const float*)d_in[6];
    const float* conv_w = (const float*)d_in[7];   // (3,128,64)
    const float* conv_b = (const float*)d_in[8];   // (3,64)
    const float* ln_g   = (const float*)d_in[9];
    const float* ln_b   = (const float*)d_in[10];
    const float* out_w  = (const float*)d_in[11];  // (64,32)
    const float* out_b  = (const float*)d_in[12];

    // workspace (~53 MB); bkt aliases agh (bucket data dead once fill2 runs)
    char* w = (char*)d_ws;
    __half* xh   = (__half*)w;  w += (size_t)NODES * HF * 2;              // 20.5 MB
    __half* agh  = (__half*)w;  w += (size_t)NODES * HF * 2;              // 20.5 MB
    unsigned* bkt = (unsigned*)agh;   // 256 buckets * 16384 * 4B = 16.8 MB
    int* cnt     = (int*)w;     w += (size_t)NODES * sizeof(int);
    int* off     = (int*)w;     w += (size_t)NODES * sizeof(int);
    int* csr     = (int*)w;     w += (size_t)NB * NE * sizeof(int);       // 10.24 MB
    int* gcur    = (int*)w;                                               // 256 ints

    hipMemsetAsync(gcur, 0, 256 * sizeof(int), stream);

    enc1_kernel<<<NODES / 256, 256, 0, stream>>>(nf, enc_w1, enc_b1, xh);
    gemm64_kernel<<<NODES / 128, 256, 0, stream>>>(xh, enc_w2, enc_b2);
    bucket_kernel<<<NB * NCHUNK, 256, 0, stream>>>(ei, gcur, bkt);
    count2_kernel<<<NB * 16, 512, 0, stream>>>(bkt, gcur, cnt);
    scan_kernel<<<NB, 256, 0, stream>>>(cnt, off);
    fill2_kernel<<<NB * 16, 512, 0, stream>>>(bkt, gcur, off, csr);

    for (int l = 0; l < 3; ++l) {
        agg_kernel<<<NODES / 4, 256, 0, stream>>>(xh, cnt, off, csr, agh);
        conv_kernel<<<NODES / 128, 256, 0, stream>>>(xh, agh,
                                                     conv_w + (size_t)l * 2 * HF * HF,
                                                     conv_b + (size_t)l * HF,
                                                     ln_g + (size_t)l * HF,
                                                     ln_b + (size_t)l * HF);
    }
    out_kernel<<<NODES / 128, 256, 0, stream>>>(xh, out_w, out_b, (float*)d_out);
}